// Round 12
// baseline (433.490 us; speedup 1.0000x reference)
//
#include <hip/hip_runtime.h>
#include <hip/hip_bf16.h>
#include <math.h>
#include <stdint.h>

// ---------------------------------------------------------------------------
// VectorTokenizer: x ->(enc MLP)-> z -> categorical(threefry key(1)) tokens
//   -> z_q = sum of codebook rows -> (dec MLP) -> rec
// Outputs: z (4096*16384) | z_q (4096*256) | rec (4096*512), f32
//
// R12: R11's fused z-GEMM + in-register sampler had a replay-only race from
// counted-vmcnt + raw s_barrier (not a compiler memory fence -> ds_reads can
// slip past the barrier before other waves' global_load_lds land). Fix: keep
// the (first-launch-validated) algorithm, switch the k-loop to plain
// __syncthreads() double-buffering (R8-proven ordering; compiler emits full
// vmcnt/lgkmcnt drains). All other kernels byte-identical to R9 (passed).
// ---------------------------------------------------------------------------

#define BATCH 4096
#define KTOK  32
#define VOCAB 512
#define DMODEL 512
#define ZDIM  16384
#define EDIM  256
#define MARGIN 0.03125f

typedef __attribute__((ext_vector_type(8))) short short8v;
typedef __attribute__((ext_vector_type(4))) float f32x4;

// ----------------------- threefry2x32 (JAX-compatible) ---------------------
__device__ __forceinline__ void threefry2x32(uint32_t k0, uint32_t k1,
                                             uint32_t x0, uint32_t x1,
                                             uint32_t& y0, uint32_t& y1) {
    uint32_t ks0 = k0, ks1 = k1, ks2 = k0 ^ k1 ^ 0x1BD11BDAu;
    x0 += ks0; x1 += ks1;
#define TFR(r) { x0 += x1; x1 = __builtin_rotateleft32(x1, r); x1 ^= x0; }
    TFR(13) TFR(15) TFR(26) TFR(6)
    x0 += ks1; x1 += ks2 + 1u;
    TFR(17) TFR(29) TFR(16) TFR(24)
    x0 += ks2; x1 += ks0 + 2u;
    TFR(13) TFR(15) TFR(26) TFR(6)
    x0 += ks0; x1 += ks1 + 3u;
    TFR(17) TFR(29) TFR(16) TFR(24)
    x0 += ks1; x1 += ks2 + 4u;
    TFR(13) TFR(15) TFR(26) TFR(6)
    x0 += ks2; x1 += ks0 + 5u;
#undef TFR
    y0 = x0; y1 = x1;
}

// 4 arbitrary counters (key=(0,1), high word 0), manually interleaved so the
// 4 chains pipeline at issue rate. Round schedule identical to R8/R9's
// proven threefry4x; only the counter inits differ.
__device__ __forceinline__ void threefry4w(uint32_t c0, uint32_t c1,
                                           uint32_t c2, uint32_t c3,
                                           uint32_t& o0, uint32_t& o1,
                                           uint32_t& o2, uint32_t& o3) {
    const uint32_t KS2 = 0x1BD11BDBu;            // 0^1^0x1BD11BDA
    uint32_t xa = 0u, ya = c0 + 1u;              // x1 init = counter + ks1
    uint32_t xb = 0u, yb = c1 + 1u;
    uint32_t xc = 0u, yc = c2 + 1u;
    uint32_t xd = 0u, yd = c3 + 1u;
#define RR(r) \
    xa += ya; xb += yb; xc += yc; xd += yd; \
    ya = __builtin_rotateleft32(ya, r) ^ xa; \
    yb = __builtin_rotateleft32(yb, r) ^ xb; \
    yc = __builtin_rotateleft32(yc, r) ^ xc; \
    yd = __builtin_rotateleft32(yd, r) ^ xd;
    RR(13) RR(15) RR(26) RR(6)
    xa += 1u; xb += 1u; xc += 1u; xd += 1u;
    ya += KS2 + 1u; yb += KS2 + 1u; yc += KS2 + 1u; yd += KS2 + 1u;
    RR(17) RR(29) RR(16) RR(24)
    xa += KS2; xb += KS2; xc += KS2; xd += KS2;
    ya += 2u; yb += 2u; yc += 2u; yd += 2u;
    RR(13) RR(15) RR(26) RR(6)
    ya += 4u; yb += 4u; yc += 4u; yd += 4u;      // ks0=0; ks1+3 = 4
    RR(17) RR(29) RR(16) RR(24)
    xa += 1u; xb += 1u; xc += 1u; xd += 1u;
    ya += KS2 + 4u; yb += KS2 + 4u; yc += KS2 + 4u; yd += KS2 + 4u;
    RR(13) RR(15) RR(26) RR(6)
    xa += KS2; xb += KS2; xc += KS2; xd += KS2;
    ya += 5u; yb += 5u; yc += 5u; yd += 5u;
#undef RR
    o0 = xa ^ ya; o1 = xb ^ yb; o2 = xc ^ yc; o3 = xd ^ yd;
}

// exact path (refine): matches JAX bit-for-bit
__device__ __forceinline__ float jax_gumbel(uint64_t e) {
    const float TINY = 1.17549435e-38f;
    uint32_t y0, y1;
    threefry2x32(0u, 1u, (uint32_t)(e >> 32), (uint32_t)(e & 0xffffffffull), y0, y1);
    uint32_t bits = y0 ^ y1;
    float u = __uint_as_float(0x3f800000u | (bits >> 9)) - 1.0f;
    u = u * 1.0f + TINY;
    u = fmaxf(TINY, u);
    return -logf(-logf(u));
}

// fast-filter gumbel: |g_fast - g_exact| <~ 1e-4 << MARGIN
__device__ __forceinline__ float gumbel_from_bits(uint32_t bits) {
    const float TINY = 1.17549435e-38f;
    const float LN2 = 0.69314718056f;
    float f = __uint_as_float(0x3f800000u | (bits >> 9));  // [1,2)
    float u = f - 1.0f;          // exact (Sterbenz)
    float d = 2.0f - f;          // exact = 1-u
    u = fmaxf(u, TINY);
    float e_hw = -LN2 * __builtin_amdgcn_logf(u);
    float e_poly = d * fmaf(d, fmaf(d, 0.33333333f, 0.5f), 1.0f);
    float e = (d < 0.002f) ? e_poly : e_hw;
    return -LN2 * __builtin_amdgcn_logf(e);
}

__device__ __forceinline__ float fast_gumbel(uint32_t e32) {
    uint32_t y0, y1;
    threefry2x32(0u, 1u, 0u, e32, y0, y1);
    return gumbel_from_bits(y0 ^ y1);
}

__device__ __forceinline__ unsigned short f32_to_bf16_rne(float f) {
    uint32_t u = __float_as_uint(f);
    uint32_t r = (u + 0x7fffu + ((u >> 16) & 1u)) >> 16;
    return (unsigned short)r;
}

// top-2 helpers (tie -> lower index wins, matching jnp.argmax)
__device__ __forceinline__ void top2_push(float& s1, float& s2, int& v1,
                                          float s, int v) {
    if (s > s1 || (s == s1 && v < v1)) { s2 = s1; s1 = s; v1 = v; }
    else s2 = fmaxf(s2, s);
}
__device__ __forceinline__ void top2_merge(float& s1, float& s2, int& v1,
                                           float os1, float os2, int ov1) {
    if (os1 > s1 || (os1 == s1 && ov1 < v1)) {
        s2 = fmaxf(s1, os2);
        s1 = os1; v1 = ov1;
    } else {
        s2 = fmaxf(s2, os1);
    }
}

__device__ __forceinline__ void gload16(const unsigned short* src,
                                        unsigned short* lds_base) {
    __builtin_amdgcn_global_load_lds(
        (const __attribute__((address_space(1))) unsigned int*)src,
        (__attribute__((address_space(3))) unsigned int*)lds_base, 16, 0, 0);
}

// ------------------ tiled f32 GEMM, 64x64 (enc1, exact) --------------------
template<bool RELU>
__global__ __launch_bounds__(256)
void gemm_f32_64(const float* __restrict__ A, const float* __restrict__ B,
                 const float* __restrict__ bias, float* __restrict__ C,
                 unsigned short* __restrict__ Cb,
                 int M, int N, int K) {
    constexpr int BK = 16;
    __shared__ __align__(16) float As[BK][68];
    __shared__ __align__(16) float Bs[BK][68];

    const int tid = threadIdx.x;
    const int tx = tid % 16;
    const int ty = tid / 16;
    const int brow = blockIdx.y * 64;
    const int bcol = blockIdx.x * 64;

    float acc[4][4] = {};

    for (int k0 = 0; k0 < K; k0 += BK) {
        {
            int r = tid >> 2, c4 = tid & 3;
            float4 v = *(const float4*)&A[(size_t)(brow + r) * K + k0 + c4 * 4];
            As[c4 * 4 + 0][r] = v.x;
            As[c4 * 4 + 1][r] = v.y;
            As[c4 * 4 + 2][r] = v.z;
            As[c4 * 4 + 3][r] = v.w;
        }
        {
            int r = tid >> 4, c4 = tid & 15;
            *(float4*)&Bs[r][c4 * 4] = *(const float4*)&B[(size_t)(k0 + r) * N + bcol + c4 * 4];
        }
        __syncthreads();

#pragma unroll
        for (int kk = 0; kk < BK; ++kk) {
            float a[4], b[4];
            *(float4*)&a[0] = *(const float4*)&As[kk][ty * 4];
            *(float4*)&b[0] = *(const float4*)&Bs[kk][tx * 4];
#pragma unroll
            for (int i = 0; i < 4; ++i)
#pragma unroll
                for (int j = 0; j < 4; ++j)
                    acc[i][j] = fmaf(a[i], b[j], acc[i][j]);
        }
        __syncthreads();
    }

#pragma unroll
    for (int i = 0; i < 4; ++i) {
        int row = brow + ty * 4 + i;
        int col = bcol + tx * 4;
        float4 v;
        v.x = acc[i][0] + bias[col + 0];
        v.y = acc[i][1] + bias[col + 1];
        v.z = acc[i][2] + bias[col + 2];
        v.w = acc[i][3] + bias[col + 3];
        if (RELU) {
            v.x = fmaxf(v.x, 0.0f); v.y = fmaxf(v.y, 0.0f);
            v.z = fmaxf(v.z, 0.0f); v.w = fmaxf(v.w, 0.0f);
        }
        *(float4*)&C[(size_t)row * N + col] = v;
        if (Cb) {
            ushort4 o;
            o.x = f32_to_bf16_rne(v.x);
            o.y = f32_to_bf16_rne(v.y);
            o.z = f32_to_bf16_rne(v.z);
            o.w = f32_to_bf16_rne(v.w);
            *(ushort4*)&Cb[(size_t)row * N + col] = o;
        }
    }
}

// ---------------- tiled f32 GEMM, 128x128 (fallback paths) -----------------
template<bool RELU>
__global__ __launch_bounds__(256)
void gemm_f32(const float* __restrict__ A, const float* __restrict__ B,
              const float* __restrict__ bias, float* __restrict__ C,
              int M, int N, int K) {
    constexpr int BM = 128, BN = 128, BK = 16, TM = 8, TN = 8;
    __shared__ __align__(16) float As[BK][BM + 4];
    __shared__ __align__(16) float Bs[BK][BN + 4];

    const int tid = threadIdx.x;
    const int tx = tid % (BN / TN);
    const int ty = tid / (BN / TN);
    const int brow = blockIdx.y * BM;
    const int bcol = blockIdx.x * BN;

    float acc[TM][TN] = {};

    for (int k0 = 0; k0 < K; k0 += BK) {
#pragma unroll
        for (int f = tid; f < BM * BK / 4; f += 256) {
            int r = f / (BK / 4);
            int c4 = f % (BK / 4);
            float4 v = *(const float4*)&A[(size_t)(brow + r) * K + k0 + c4 * 4];
            As[c4 * 4 + 0][r] = v.x;
            As[c4 * 4 + 1][r] = v.y;
            As[c4 * 4 + 2][r] = v.z;
            As[c4 * 4 + 3][r] = v.w;
        }
#pragma unroll
        for (int f = tid; f < BK * BN / 4; f += 256) {
            int r = f / (BN / 4);
            int c4 = f % (BN / 4);
            *(float4*)&Bs[r][c4 * 4] = *(const float4*)&B[(size_t)(k0 + r) * N + bcol + c4 * 4];
        }
        __syncthreads();

#pragma unroll
        for (int kk = 0; kk < BK; ++kk) {
            float a[TM], b[TN];
            *(float4*)&a[0] = *(const float4*)&As[kk][ty * TM];
            *(float4*)&a[4] = *(const float4*)&As[kk][ty * TM + 4];
            *(float4*)&b[0] = *(const float4*)&Bs[kk][tx * TN];
            *(float4*)&b[4] = *(const float4*)&Bs[kk][tx * TN + 4];
#pragma unroll
            for (int i = 0; i < TM; ++i)
#pragma unroll
                for (int j = 0; j < TN; ++j)
                    acc[i][j] = fmaf(a[i], b[j], acc[i][j]);
        }
        __syncthreads();
    }

#pragma unroll
    for (int i = 0; i < TM; ++i) {
        int row = brow + ty * TM + i;
#pragma unroll
        for (int j = 0; j < TN; j += 4) {
            int col = bcol + tx * TN + j;
            float4 v;
            v.x = acc[i][j + 0] + bias[col + 0];
            v.y = acc[i][j + 1] + bias[col + 1];
            v.z = acc[i][j + 2] + bias[col + 2];
            v.w = acc[i][j + 3] + bias[col + 3];
            if (RELU) {
                v.x = fmaxf(v.x, 0.0f); v.y = fmaxf(v.y, 0.0f);
                v.z = fmaxf(v.z, 0.0f); v.w = fmaxf(v.w, 0.0f);
            }
            *(float4*)&C[(size_t)row * N + col] = v;
        }
    }
}

// ---- f32 [R][C] -> bf16 [C][R] transpose (+ optional f32 [C][R]) ----------
__global__ __launch_bounds__(256)
void transpose_w2(const float* __restrict__ src, unsigned short* __restrict__ dstb,
                  float* __restrict__ dstf, int R, int C, int writeF) {
    __shared__ float tile[32][33];
    const int c0 = blockIdx.x * 32, r0 = blockIdx.y * 32;
    const int tx = threadIdx.x % 32, ty = threadIdx.x / 32;
#pragma unroll
    for (int i = ty; i < 32; i += 8)
        tile[i][tx] = src[(size_t)(r0 + i) * C + c0 + tx];
    __syncthreads();
#pragma unroll
    for (int i = ty; i < 32; i += 8) {
        float v = tile[tx][i];
        size_t o = (size_t)(c0 + i) * R + r0 + tx;
        dstb[o] = f32_to_bf16_rne(v);
        if (writeF) dstf[o] = v;
    }
}

// ------- bf16 MFMA GEMM (decoder), 3-buf counted-vmcnt pipeline ------------
// Byte-identical to R9 (passed replay validation).
template<bool RELU, bool WF32, bool WBF16>
__global__ __launch_bounds__(256)
void gemm_mfma(const unsigned short* __restrict__ A,
               const unsigned short* __restrict__ Bt,
               const float* __restrict__ bias,
               float* __restrict__ C, unsigned short* __restrict__ Cb,
               int M, int N, int K) {
    constexpr int BM = 128, BN = 128, BK = 32;
    constexpr int TSZ = BM * BK;
    __shared__ unsigned short As[3 * TSZ];
    __shared__ unsigned short Bs[3 * TSZ];

    const int lid = blockIdx.y * gridDim.x + blockIdx.x;
    const int xcd = lid & 7;
    const int kk2 = lid >> 3;
    const int rpx = gridDim.y >> 3;
    const int by = xcd * rpx + (kk2 % rpx);
    const int bx = kk2 / rpx;

    const int tid = threadIdx.x;
    const int wid = tid >> 6;
    const int lane = tid & 63;
    const int wr = wid >> 1, wc = wid & 1;
    const int l15 = lane & 15, lq = lane >> 4;
    const int brow = by * BM;
    const int bcol = bx * BN;

    const int g1 = tid;
    const int g2 = tid + 256;
    const size_t a1 = (size_t)(brow + (g1 >> 2)) * K + (g1 & 3) * 8;
    const size_t a2 = (size_t)(brow + (g2 >> 2)) * K + (g2 & 3) * 8;
    const size_t b1 = (size_t)(bcol + (g1 >> 2)) * K + (g1 & 3) * 8;
    const size_t b2 = (size_t)(bcol + (g2 >> 2)) * K + (g2 & 3) * 8;
    const int off1 = wid * 64 * 8;
    const int off2 = (256 + wid * 64) * 8;

    f32x4 acc[4][4];
#pragma unroll
    for (int m = 0; m < 4; ++m)
#pragma unroll
        for (int n = 0; n < 4; ++n) acc[m][n] = (f32x4){0.f, 0.f, 0.f, 0.f};

    const int NK = K / BK;

#define STAGE(kt, bufi) { \
    const int k0_ = (kt) * BK; \
    const int o_ = (bufi) * TSZ; \
    gload16(A + a1 + k0_, As + o_ + off1); \
    gload16(A + a2 + k0_, As + o_ + off2); \
    gload16(Bt + b1 + k0_, Bs + o_ + off1); \
    gload16(Bt + b2 + k0_, Bs + o_ + off2); }

    STAGE(0, 0)
    if (NK > 1) STAGE(1, 1)

    int buf = 0;
    for (int kt = 0; kt < NK; ++kt) {
        if (kt + 2 < NK) {
            int nb = buf + 2; if (nb >= 3) nb -= 3;
            STAGE(kt + 2, nb)
        }
        if (kt + 2 < NK)      asm volatile("s_waitcnt vmcnt(8)" ::: "memory");
        else if (kt + 1 < NK) asm volatile("s_waitcnt vmcnt(4)" ::: "memory");
        else                  asm volatile("s_waitcnt vmcnt(0)" ::: "memory");
        __builtin_amdgcn_s_barrier();
        __builtin_amdgcn_sched_barrier(0);

        const int cb = buf * TSZ;
        short8v af[4], bf[4];
#pragma unroll
        for (int m = 0; m < 4; ++m)
            af[m] = *(const short8v*)&As[cb + (wr * 64 + m * 16 + l15) * BK + lq * 8];
#pragma unroll
        for (int n = 0; n < 4; ++n)
            bf[n] = *(const short8v*)&Bs[cb + (wc * 64 + n * 16 + l15) * BK + lq * 8];
#pragma unroll
        for (int m = 0; m < 4; ++m)
#pragma unroll
            for (int n = 0; n < 4; ++n)
                acc[m][n] = __builtin_amdgcn_mfma_f32_16x16x32_bf16(
                    af[m], bf[n], acc[m][n], 0, 0, 0);
        __builtin_amdgcn_s_barrier();
        ++buf; if (buf == 3) buf = 0;
    }
#undef STAGE

#pragma unroll
    for (int m = 0; m < 4; ++m) {
#pragma unroll
        for (int n = 0; n < 4; ++n) {
            int col = bcol + wc * 64 + n * 16 + l15;
            float bv = bias[col];
#pragma unroll
            for (int r = 0; r < 4; ++r) {
                int row = brow + wr * 64 + m * 16 + lq * 4 + r;
                float v = acc[m][n][r] + bv;
                if (RELU) v = fmaxf(v, 0.0f);
                if (WF32) C[(size_t)row * N + col] = v;
                if (WBF16) Cb[(size_t)row * N + col] = f32_to_bf16_rne(v);
            }
        }
    }
}

// ----- fused z-GEMM + in-register top-2 sampler (syncthreads-only) ---------
// 1024 blocks; block = (panel p, group grp): 128 rows x 512 cols. 4 sub-tiles
// of 128x128 computed sequentially; per sub the epilogue folds acc into
// per-row running top-2 (z never re-read). All LDS ordering via
// __syncthreads() (full drains: R8-proven correct). 4 blocks/CU co-resident:
// sampling VALU overlaps other blocks' MFMA/memory phases (m114).
__global__ __launch_bounds__(256, 4)
void gemm_fused_topk(const unsigned short* __restrict__ A,
                     const unsigned short* __restrict__ Bt,
                     const float* __restrict__ bias,
                     float* __restrict__ z,
                     int* __restrict__ tokens, float* __restrict__ s1v,
                     int* __restrict__ amb, int* __restrict__ ambCount,
                     int K) {
    constexpr int BM = 128, BK = 32, TSZ = BM * BK;
    __shared__ unsigned short As[2 * TSZ];
    __shared__ unsigned short Bs[2 * TSZ];
    __shared__ float pS1[BM][2], pS2[BM][2];
    __shared__ int   pV[BM][2];

    const int lid = blockIdx.x;                  // 0..1023
    const int xcd = lid & 7;
    const int q = lid >> 3;                      // 0..127
    const int p = xcd * 4 + (q & 3);             // panel 0..31 (4 per XCD)
    const int grp = q >> 2;                      // vocab group 0..31
    const int brow = p * BM;

    const int tid = threadIdx.x;
    const int wid = tid >> 6;
    const int lane = tid & 63;
    const int wr = wid >> 1, wc = wid & 1;
    const int l15 = lane & 15, lq = lane >> 4;

    const int g1 = tid;
    const int g2 = tid + 256;
    const size_t a1 = (size_t)(brow + (g1 >> 2)) * K + (g1 & 3) * 8;
    const size_t a2 = (size_t)(brow + (g2 >> 2)) * K + (g2 & 3) * 8;
    const int off1 = wid * 64 * 8;
    const int off2 = (256 + wid * 64) * 8;
    const int NK = K / BK;

    float rs1 = -INFINITY, rs2 = -INFINITY;      // running top-2 for row tid
    int rv1 = VOCAB;

#pragma unroll 1
    for (int sub = 0; sub < 4; ++sub) {
        const int bcol = grp * 512 + sub * 128;
        const size_t b1 = (size_t)(bcol + (g1 >> 2)) * K + (g1 & 3) * 8;
        const size_t b2 = (size_t)(bcol + (g2 >> 2)) * K + (g2 & 3) * 8;

        f32x4 acc[4][4];
#pragma unroll
        for (int m = 0; m < 4; ++m)
#pragma unroll
            for (int n = 0; n < 4; ++n) acc[m][n] = (f32x4){0.f, 0.f, 0.f, 0.f};

#define STAGE(kt, bufi) { \
    const int k0_ = (kt) * BK; \
    const int o_ = (bufi) * TSZ; \
    gload16(A + a1 + k0_, As + o_ + off1); \
    gload16(A + a2 + k0_, As + o_ + off2); \
    gload16(Bt + b1 + k0_, Bs + o_ + off1); \
    gload16(Bt + b2 + k0_, Bs + o_ + off2); }

        STAGE(0, 0)
        __syncthreads();                          // drains STAGE(0)
        int buf = 0;
        for (int kt = 0; kt < NK; ++kt) {
            if (kt + 1 < NK) STAGE(kt + 1, buf ^ 1)

            const int cb = buf * TSZ;
            short8v af[4], bf[4];
#pragma unroll
            for (int m = 0; m < 4; ++m)
                af[m] = *(const short8v*)&As[cb + (wr * 64 + m * 16 + l15) * BK + lq * 8];
#pragma unroll
            for (int n = 0; n < 4; ++n)
                bf[n] = *(const short8v*)&Bs[cb + (wc * 64 + n * 16 + l15) * BK + lq * 8];
#pragma unroll
            for (int m = 0; m < 4; ++m)
#pragma unroll
                for (int n = 0; n < 4; ++n)
                    acc[m][n] = __builtin_amdgcn_mfma_f32_16x16x32_bf16(
                        af[m], bf[n], acc[m][n], 0, 0, 0);
            __syncthreads();                      // full drain: next buf ready
            buf ^= 1;
        }
#undef STAGE

        // ---- epilogue: z write + fold into per-row top-2 ----
        float bv[4];
#pragma unroll
        for (int n = 0; n < 4; ++n)
            bv[n] = bias[bcol + wc * 64 + n * 16 + l15];

#pragma unroll
        for (int m = 0; m < 4; ++m) {
#pragma unroll
            for (int r = 0; r < 4; ++r) {
                const int lrow = wr * 64 + m * 16 + lq * 4 + r;   // 0..127
                const int row = brow + lrow;
                const uint32_t t = (uint32_t)row * KTOK + grp;
                const int vbase = sub * 128 + wc * 64 + l15;      // + n*16
                float val[4];
#pragma unroll
                for (int n = 0; n < 4; ++n) {
                    val[n] = acc[m][n][r] + bv[n];
                    z[(size_t)row * ZDIM + (size_t)grp * VOCAB + vbase + n * 16] = val[n];
                }
                const uint32_t eb = t * (uint32_t)VOCAB + (uint32_t)vbase;
                uint32_t b0, b1_, b2_, b3_;
                threefry4w(eb, eb + 16, eb + 32, eb + 48, b0, b1_, b2_, b3_);
                float s1 = -INFINITY, s2 = -INFINITY;
                int v1 = VOCAB;
                top2_push(s1, s2, v1, val[0] + gumbel_from_bits(b0),  vbase);
                top2_push(s1, s2, v1, val[1] + gumbel_from_bits(b1_), vbase + 16);
                top2_push(s1, s2, v1, val[2] + gumbel_from_bits(b2_), vbase + 32);
                top2_push(s1, s2, v1, val[3] + gumbel_from_bits(b3_), vbase + 48);
#pragma unroll
                for (int off = 1; off < 16; off <<= 1) {
                    float os1 = __shfl_xor(s1, off);
                    float os2 = __shfl_xor(s2, off);
                    int   ov1 = __shfl_xor(v1, off);
                    top2_merge(s1, s2, v1, os1, os2, ov1);
                }
                if (l15 == 0) {
                    pS1[lrow][wc] = s1; pS2[lrow][wc] = s2; pV[lrow][wc] = v1;
                }
            }
        }
        __syncthreads();
        if (tid < BM) {
            top2_merge(rs1, rs2, rv1, pS1[tid][0], pS2[tid][0], pV[tid][0]);
            top2_merge(rs1, rs2, rv1, pS1[tid][1], pS2[tid][1], pV[tid][1]);
        }
        __syncthreads();   // pS*/pV free for next sub
    }

    if (tid < BM) {
        const int row = brow + tid;
        const uint32_t t = (uint32_t)row * KTOK + grp;
        tokens[t] = rv1;
        s1v[t] = rs1;
        if (rs1 - rs2 < MARGIN) {
            int i = atomicAdd(ambCount, 1);
            amb[i] = (int)t;
        }
    }
}

// ------ refine: w2t f32 rows, ballot-compacted candidates ------------------
__global__ __launch_bounds__(64)
void refine_tokens2(const float* __restrict__ z, const float* __restrict__ h,
                    const float* __restrict__ w2t, const float* __restrict__ eb2,
                    const int* __restrict__ amb, const int* __restrict__ ambCount,
                    const float* __restrict__ s1v, int* __restrict__ tok) {
    __shared__ float hrow[DMODEL];
    __shared__ int candv[64];
    const int cnt = *ambCount;
    const int lane = threadIdx.x;

    for (int i = blockIdx.x; i < cnt; i += gridDim.x) {
        const int t = amb[i];
        const int b = t >> 5;
        const int kb = t & 31;
        const float* zr = z + (size_t)t * VOCAB;
        const float s1 = s1v[t];

        {
            float4 hv0 = *(const float4*)&h[(size_t)b * DMODEL + lane * 8];
            float4 hv1 = *(const float4*)&h[(size_t)b * DMODEL + lane * 8 + 4];
            *(float4*)&hrow[lane * 8] = hv0;
            *(float4*)&hrow[lane * 8 + 4] = hv1;
        }

        int base = 0;
#pragma unroll
        for (int half = 0; half < 2; ++half) {
            int e0 = half * 256 + lane * 4;
            float4 zv = *(const float4*)&zr[e0];
            float zs[4] = {zv.x, zv.y, zv.z, zv.w};
#pragma unroll
            for (int j = 0; j < 4; ++j) {
                int v = e0 + j;
                float s = zs[j] + fast_gumbel((uint32_t)t * VOCAB + v);
                bool pred = (s >= s1 - MARGIN);
                unsigned long long mask = __ballot(pred);
                if (pred) {
                    int slot = base + __popcll(mask & ((1ull << lane) - 1ull));
                    if (slot < 64) candv[slot] = v;
                }
                base += __popcll(mask);
            }
        }
        __syncthreads();
        const int ncand = base < 64 ? base : 64;

        float bestE = -INFINITY;
        int bestV = VOCAB;
        if (lane < ncand) {
            const int v = candv[lane];
            const int n = kb * VOCAB + v;
            const float* wr_ = w2t + (size_t)n * DMODEL;
            float acc = 0.f;
#pragma unroll 8
            for (int k = 0; k < DMODEL; ++k)
                acc = fmaf(hrow[k], wr_[k], acc);
            bestE = acc + eb2[n] + jax_gumbel((uint64_t)t * VOCAB + v);
            bestV = v;
        }
#pragma unroll
        for (int off = 32; off > 0; off >>= 1) {
            float oe = __shfl_down(bestE, off);
            int ov = __shfl_down(bestV, off);
            if (oe > bestE || (oe == bestE && ov < bestV)) { bestE = oe; bestV = ov; }
        }
        if (lane == 0) tok[t] = bestV;
        __syncthreads();
    }
}

// ----------------- simple sampler (ws-too-small fallback) ------------------
__global__ __launch_bounds__(256)
void sample_tokens_simple(const float* __restrict__ z, int* __restrict__ tokens) {
    const int wave = threadIdx.x >> 6;
    const int lane = threadIdx.x & 63;
    const size_t t = (size_t)blockIdx.x * 4 + wave;
    const float* zr = z + t * VOCAB;
    float zv[8];
    *(float4*)&zv[0] = *(const float4*)&zr[lane * 8];
    *(float4*)&zv[4] = *(const float4*)&zr[lane * 8 + 4];
    const uint64_t ebase = t * (uint64_t)VOCAB + (uint64_t)lane * 8;
    float best = -INFINITY;
    int bestv = 0;
#pragma unroll
    for (int j = 0; j < 8; ++j) {
        float g = jax_gumbel(ebase + j);
        float s = zv[j] + g;
        int v = lane * 8 + j;
        if (s > best || (s == best && v < bestv)) { best = s; bestv = v; }
    }
#pragma unroll
    for (int off = 32; off > 0; off >>= 1) {
        float ob = __shfl_down(best, off);
        int ov = __shfl_down(bestv, off);
        if (ob > best || (ob == best && ov < bestv)) { best = ob; bestv = ov; }
    }
    if (lane == 0) tokens[t] = bestv;
}

__global__ __launch_bounds__(64)
void zero_count(int* p) { if (threadIdx.x == 0) *p = 0; }

// ---------------- z_q gather (exact f32 + optional bf16 copy) --------------
__global__ __launch_bounds__(256)
void gather_zq(const int* __restrict__ tokens, const float* __restrict__ codebook,
               float* __restrict__ zq, unsigned short* __restrict__ zqb) {
    const int b = blockIdx.x;
    const int d = threadIdx.x;
    float s = 0.0f;
#pragma unroll
    for (int k = 0; k < KTOK; ++k) {
        int tok = tokens[b * KTOK + k];
        s += codebook[(size_t)(k * VOCAB + tok) * EDIM + d];
    }
    zq[(size_t)b * EDIM + d] = s;
    if (zqb) zqb[(size_t)b * EDIM + d] = f32_to_bf16_rne(s);
}

// ------------------------------- launcher ----------------------------------
extern "C" void kernel_launch(void* const* d_in, const int* in_sizes, int n_in,
                              void* d_out, int out_size, void* d_ws, size_t ws_size,
                              hipStream_t stream) {
    const float* x   = (const float*)d_in[0];
    const float* ew1 = (const float*)d_in[1];
    const float* eb1 = (const float*)d_in[2];
    const float* ew2 = (const float*)d_in[3];
    const float* eb2 = (const float*)d_in[4];
    const float* cb  = (const float*)d_in[5];
    const float* dw1 = (const float*)d_in[6];
    const float* db1 = (const float*)d_in[7];
    const float* dw2 = (const float*)d_in[8];
    const float* db2 = (const float*)d_in[9];

    float* out = (float*)d_out;
    float* z   = out;
    float* zq  = out + (size_t)BATCH * ZDIM;
    float* rec = zq + (size_t)BATCH * EDIM;

    char* ws = (char*)d_ws;
    float* h    = (float*)(ws);                               // 8 MB
    unsigned short* zqb   = (unsigned short*)(ws + 8388608);  // 2 MB
    unsigned short* h2b   = (unsigned short*)(ws + 10485760); // 4 MB
    unsigned short* dw1tb = (unsigned short*)(ws + 14680064); // 256 KB
    unsigned short* dw2tb = (unsigned short*)(ws + 14942208); // 512 KB
    float* h2f  = (float*)(ws + 8388608);                     // fallback f32 h2
    unsigned short* hb   = (unsigned short*)(ws + 16777216);  // 4 MB
    unsigned short* w2bt = (unsigned short*)(ws + 20971520);  // 16 MB
    float* w2t  = (float*)(ws + 37748736);                    // 32 MB
    char* tail = ws + 71303168;
    const size_t WS_NEED2 = 71303168 + 1572864 + 256;         // ~72.9 MB
    const bool fast2 = ws_size >= WS_NEED2;
    if (!fast2) tail = ws + 16777216;
    int*   tok  = (int*)(tail);
    float* s1v  = (float*)(tail + 524288);
    int*   amb  = (int*)(tail + 1048576);
    int*   cnt  = (int*)(tail + 1572864);

    dim3 blk(256);

    // encoder layer 1 (f32 exact; bf16 copy fused when fast2)
    gemm_f32_64<true ><<<dim3(DMODEL / 64, BATCH / 64), blk, 0, stream>>>(
        x, ew1, eb1, h, fast2 ? hb : (unsigned short*)nullptr,
        BATCH, DMODEL, DMODEL);

    if (fast2) {
        transpose_w2<<<dim3(ZDIM / 32, DMODEL / 32), blk, 0, stream>>>(
            ew2, w2bt, w2t, DMODEL, ZDIM, 1);
        transpose_w2<<<dim3(DMODEL / 32, EDIM / 32), blk, 0, stream>>>(
            dw1, dw1tb, nullptr, EDIM, DMODEL, 0);
        transpose_w2<<<dim3(DMODEL / 32, DMODEL / 32), blk, 0, stream>>>(
            dw2, dw2tb, nullptr, DMODEL, DMODEL, 0);
        zero_count<<<dim3(1), dim3(64), 0, stream>>>(cnt);
        // fused z-GEMM + in-register sampler (syncthreads-only ordering)
        gemm_fused_topk<<<dim3(1024), blk, 0, stream>>>(
            hb, w2bt, eb2, z, tok, s1v, amb, cnt, DMODEL);
        refine_tokens2<<<dim3(4096), dim3(64), 0, stream>>>(
            z, h, w2t, eb2, amb, cnt, s1v, tok);
        gather_zq<<<dim3(BATCH), blk, 0, stream>>>(tok, cb, zq, zqb);
        // decoder via bf16 MFMA (R9-proven)
        gemm_mfma<true, false, true><<<dim3(DMODEL / 128, BATCH / 128), blk, 0, stream>>>(
            zqb, dw1tb, db1, nullptr, h2b, BATCH, DMODEL, EDIM);
        gemm_mfma<false, true, false><<<dim3(DMODEL / 128, BATCH / 128), blk, 0, stream>>>(
            h2b, dw2tb, db2, rec, nullptr, BATCH, DMODEL, DMODEL);
    } else {
        gemm_f32<false><<<dim3(ZDIM / 128, BATCH / 128), blk, 0, stream>>>(
            h, ew2, eb2, z, BATCH, ZDIM, DMODEL);
        sample_tokens_simple<<<dim3(BATCH * KTOK / 4), blk, 0, stream>>>(z, tok);
        gather_zq<<<dim3(BATCH), blk, 0, stream>>>(tok, cb, zq, nullptr);
        gemm_f32_64<true ><<<dim3(DMODEL / 64, BATCH / 64), blk, 0, stream>>>(
            zq, dw1, db1, h2f, nullptr, BATCH, DMODEL, EDIM);
        gemm_f32_64<false><<<dim3(DMODEL / 64, BATCH / 64), blk, 0, stream>>>(
            h2f, dw2, db2, rec, nullptr, BATCH, DMODEL, DMODEL);
    }
}

// Round 13
// 395.248 us; speedup vs baseline: 1.0968x; 1.0968x over previous
//
#include <hip/hip_runtime.h>
#include <hip/hip_bf16.h>
#include <math.h>
#include <stdint.h>

// ---------------------------------------------------------------------------
// VectorTokenizer: x ->(enc MLP)-> z -> categorical(threefry key(1)) tokens
//   -> z_q = sum of codebook rows -> (dec MLP) -> rec
// Outputs: z (4096*16384) | z_q (4096*256) | rec (4096*512), f32
//
// R13 = R9 exact (passed, 395 us). Fusion of GEMM+sampler abandoned after
// three failures (R5/R6 occupancy mismatch, R10 fence corruption, R12
// lockstep no-overlap): homogeneous grids give no phase diversity, so the
// sampler's VALU never overlaps the GEMM's MFMA across blocks. Structure:
// exact f32 enc1 (+fused bf16 copy), counted-vmcnt 3-buf bf16 MFMA z-GEMM,
// max-only ILP-4 threefry sampler (VALU-issue floor, proven by two null
// experiments), exact sparse refine, exact z_q gather, bf16 MFMA decoder.
// ---------------------------------------------------------------------------

#define BATCH 4096
#define KTOK  32
#define VOCAB 512
#define DMODEL 512
#define ZDIM  16384
#define EDIM  256
#define MARGIN 0.03125f

typedef __attribute__((ext_vector_type(8))) short short8v;
typedef __attribute__((ext_vector_type(4))) float f32x4;

// ----------------------- threefry2x32 (JAX-compatible) ---------------------
__device__ __forceinline__ void threefry2x32(uint32_t k0, uint32_t k1,
                                             uint32_t x0, uint32_t x1,
                                             uint32_t& y0, uint32_t& y1) {
    uint32_t ks0 = k0, ks1 = k1, ks2 = k0 ^ k1 ^ 0x1BD11BDAu;
    x0 += ks0; x1 += ks1;
#define TFR(r) { x0 += x1; x1 = __builtin_rotateleft32(x1, r); x1 ^= x0; }
    TFR(13) TFR(15) TFR(26) TFR(6)
    x0 += ks1; x1 += ks2 + 1u;
    TFR(17) TFR(29) TFR(16) TFR(24)
    x0 += ks2; x1 += ks0 + 2u;
    TFR(13) TFR(15) TFR(26) TFR(6)
    x0 += ks0; x1 += ks1 + 3u;
    TFR(17) TFR(29) TFR(16) TFR(24)
    x0 += ks1; x1 += ks2 + 4u;
    TFR(13) TFR(15) TFR(26) TFR(6)
    x0 += ks2; x1 += ks0 + 5u;
#undef TFR
    y0 = x0; y1 = x1;
}

// 4 consecutive counters, manually interleaved (issue-rate pipelining)
__device__ __forceinline__ void threefry4x(uint32_t e,
                                           uint32_t& o0, uint32_t& o1,
                                           uint32_t& o2, uint32_t& o3) {
    const uint32_t KS2 = 0x1BD11BDBu;
    uint32_t xa = 0u, ya = e + 1u;
    uint32_t xb = 0u, yb = e + 2u;
    uint32_t xc = 0u, yc = e + 3u;
    uint32_t xd = 0u, yd = e + 4u;
#define RR(r) \
    xa += ya; xb += yb; xc += yc; xd += yd; \
    ya = __builtin_rotateleft32(ya, r) ^ xa; \
    yb = __builtin_rotateleft32(yb, r) ^ xb; \
    yc = __builtin_rotateleft32(yc, r) ^ xc; \
    yd = __builtin_rotateleft32(yd, r) ^ xd;
    RR(13) RR(15) RR(26) RR(6)
    xa += 1u; xb += 1u; xc += 1u; xd += 1u;
    ya += KS2 + 1u; yb += KS2 + 1u; yc += KS2 + 1u; yd += KS2 + 1u;
    RR(17) RR(29) RR(16) RR(24)
    xa += KS2; xb += KS2; xc += KS2; xd += KS2;
    ya += 2u; yb += 2u; yc += 2u; yd += 2u;
    RR(13) RR(15) RR(26) RR(6)
    ya += 4u; yb += 4u; yc += 4u; yd += 4u;
    RR(17) RR(29) RR(16) RR(24)
    xa += 1u; xb += 1u; xc += 1u; xd += 1u;
    ya += KS2 + 4u; yb += KS2 + 4u; yc += KS2 + 4u; yd += KS2 + 4u;
    RR(13) RR(15) RR(26) RR(6)
    xa += KS2; xb += KS2; xc += KS2; xd += KS2;
    ya += 5u; yb += 5u; yc += 5u; yd += 5u;
#undef RR
    o0 = xa ^ ya; o1 = xb ^ yb; o2 = xc ^ yc; o3 = xd ^ yd;
}

// exact path (refine): matches JAX bit-for-bit
__device__ __forceinline__ float jax_gumbel(uint64_t e) {
    const float TINY = 1.17549435e-38f;
    uint32_t y0, y1;
    threefry2x32(0u, 1u, (uint32_t)(e >> 32), (uint32_t)(e & 0xffffffffull), y0, y1);
    uint32_t bits = y0 ^ y1;
    float u = __uint_as_float(0x3f800000u | (bits >> 9)) - 1.0f;
    u = u * 1.0f + TINY;
    u = fmaxf(TINY, u);
    return -logf(-logf(u));
}

// fast-filter gumbel: |g_fast - g_exact| <~ 1e-4 << MARGIN
__device__ __forceinline__ float gumbel_from_bits(uint32_t bits) {
    const float TINY = 1.17549435e-38f;
    const float LN2 = 0.69314718056f;
    float f = __uint_as_float(0x3f800000u | (bits >> 9));  // [1,2)
    float u = f - 1.0f;          // exact (Sterbenz)
    float d = 2.0f - f;          // exact = 1-u
    u = fmaxf(u, TINY);
    float e_hw = -LN2 * __builtin_amdgcn_logf(u);
    float e_poly = d * fmaf(d, fmaf(d, 0.33333333f, 0.5f), 1.0f);
    float e = (d < 0.002f) ? e_poly : e_hw;
    return -LN2 * __builtin_amdgcn_logf(e);
}

__device__ __forceinline__ float fast_gumbel(uint32_t e32) {
    uint32_t y0, y1;
    threefry2x32(0u, 1u, 0u, e32, y0, y1);
    return gumbel_from_bits(y0 ^ y1);
}

__device__ __forceinline__ unsigned short f32_to_bf16_rne(float f) {
    uint32_t u = __float_as_uint(f);
    uint32_t r = (u + 0x7fffu + ((u >> 16) & 1u)) >> 16;
    return (unsigned short)r;
}

__device__ __forceinline__ void gload16(const unsigned short* src,
                                        unsigned short* lds_base) {
    __builtin_amdgcn_global_load_lds(
        (const __attribute__((address_space(1))) unsigned int*)src,
        (__attribute__((address_space(3))) unsigned int*)lds_base, 16, 0, 0);
}

// ------------------ tiled f32 GEMM, 64x64 (enc1, exact) --------------------
template<bool RELU>
__global__ __launch_bounds__(256)
void gemm_f32_64(const float* __restrict__ A, const float* __restrict__ B,
                 const float* __restrict__ bias, float* __restrict__ C,
                 unsigned short* __restrict__ Cb,
                 int M, int N, int K) {
    constexpr int BK = 16;
    __shared__ __align__(16) float As[BK][68];
    __shared__ __align__(16) float Bs[BK][68];

    const int tid = threadIdx.x;
    const int tx = tid % 16;
    const int ty = tid / 16;
    const int brow = blockIdx.y * 64;
    const int bcol = blockIdx.x * 64;

    float acc[4][4] = {};

    for (int k0 = 0; k0 < K; k0 += BK) {
        {
            int r = tid >> 2, c4 = tid & 3;
            float4 v = *(const float4*)&A[(size_t)(brow + r) * K + k0 + c4 * 4];
            As[c4 * 4 + 0][r] = v.x;
            As[c4 * 4 + 1][r] = v.y;
            As[c4 * 4 + 2][r] = v.z;
            As[c4 * 4 + 3][r] = v.w;
        }
        {
            int r = tid >> 4, c4 = tid & 15;
            *(float4*)&Bs[r][c4 * 4] = *(const float4*)&B[(size_t)(k0 + r) * N + bcol + c4 * 4];
        }
        __syncthreads();

#pragma unroll
        for (int kk = 0; kk < BK; ++kk) {
            float a[4], b[4];
            *(float4*)&a[0] = *(const float4*)&As[kk][ty * 4];
            *(float4*)&b[0] = *(const float4*)&Bs[kk][tx * 4];
#pragma unroll
            for (int i = 0; i < 4; ++i)
#pragma unroll
                for (int j = 0; j < 4; ++j)
                    acc[i][j] = fmaf(a[i], b[j], acc[i][j]);
        }
        __syncthreads();
    }

#pragma unroll
    for (int i = 0; i < 4; ++i) {
        int row = brow + ty * 4 + i;
        int col = bcol + tx * 4;
        float4 v;
        v.x = acc[i][0] + bias[col + 0];
        v.y = acc[i][1] + bias[col + 1];
        v.z = acc[i][2] + bias[col + 2];
        v.w = acc[i][3] + bias[col + 3];
        if (RELU) {
            v.x = fmaxf(v.x, 0.0f); v.y = fmaxf(v.y, 0.0f);
            v.z = fmaxf(v.z, 0.0f); v.w = fmaxf(v.w, 0.0f);
        }
        *(float4*)&C[(size_t)row * N + col] = v;
        if (Cb) {
            ushort4 o;
            o.x = f32_to_bf16_rne(v.x);
            o.y = f32_to_bf16_rne(v.y);
            o.z = f32_to_bf16_rne(v.z);
            o.w = f32_to_bf16_rne(v.w);
            *(ushort4*)&Cb[(size_t)row * N + col] = o;
        }
    }
}

// ---------------- tiled f32 GEMM, 128x128 (fallback paths) -----------------
template<bool RELU>
__global__ __launch_bounds__(256)
void gemm_f32(const float* __restrict__ A, const float* __restrict__ B,
              const float* __restrict__ bias, float* __restrict__ C,
              int M, int N, int K) {
    constexpr int BM = 128, BN = 128, BK = 16, TM = 8, TN = 8;
    __shared__ __align__(16) float As[BK][BM + 4];
    __shared__ __align__(16) float Bs[BK][BN + 4];

    const int tid = threadIdx.x;
    const int tx = tid % (BN / TN);
    const int ty = tid / (BN / TN);
    const int brow = blockIdx.y * BM;
    const int bcol = blockIdx.x * BN;

    float acc[TM][TN] = {};

    for (int k0 = 0; k0 < K; k0 += BK) {
#pragma unroll
        for (int f = tid; f < BM * BK / 4; f += 256) {
            int r = f / (BK / 4);
            int c4 = f % (BK / 4);
            float4 v = *(const float4*)&A[(size_t)(brow + r) * K + k0 + c4 * 4];
            As[c4 * 4 + 0][r] = v.x;
            As[c4 * 4 + 1][r] = v.y;
            As[c4 * 4 + 2][r] = v.z;
            As[c4 * 4 + 3][r] = v.w;
        }
#pragma unroll
        for (int f = tid; f < BK * BN / 4; f += 256) {
            int r = f / (BN / 4);
            int c4 = f % (BN / 4);
            *(float4*)&Bs[r][c4 * 4] = *(const float4*)&B[(size_t)(k0 + r) * N + bcol + c4 * 4];
        }
        __syncthreads();

#pragma unroll
        for (int kk = 0; kk < BK; ++kk) {
            float a[TM], b[TN];
            *(float4*)&a[0] = *(const float4*)&As[kk][ty * TM];
            *(float4*)&a[4] = *(const float4*)&As[kk][ty * TM + 4];
            *(float4*)&b[0] = *(const float4*)&Bs[kk][tx * TN];
            *(float4*)&b[4] = *(const float4*)&Bs[kk][tx * TN + 4];
#pragma unroll
            for (int i = 0; i < TM; ++i)
#pragma unroll
                for (int j = 0; j < TN; ++j)
                    acc[i][j] = fmaf(a[i], b[j], acc[i][j]);
        }
        __syncthreads();
    }

#pragma unroll
    for (int i = 0; i < TM; ++i) {
        int row = brow + ty * TM + i;
#pragma unroll
        for (int j = 0; j < TN; j += 4) {
            int col = bcol + tx * TN + j;
            float4 v;
            v.x = acc[i][j + 0] + bias[col + 0];
            v.y = acc[i][j + 1] + bias[col + 1];
            v.z = acc[i][j + 2] + bias[col + 2];
            v.w = acc[i][j + 3] + bias[col + 3];
            if (RELU) {
                v.x = fmaxf(v.x, 0.0f); v.y = fmaxf(v.y, 0.0f);
                v.z = fmaxf(v.z, 0.0f); v.w = fmaxf(v.w, 0.0f);
            }
            *(float4*)&C[(size_t)row * N + col] = v;
        }
    }
}

// ---- f32 [R][C] -> bf16 [C][R] transpose (+ optional f32 [C][R]) ----------
__global__ __launch_bounds__(256)
void transpose_w2(const float* __restrict__ src, unsigned short* __restrict__ dstb,
                  float* __restrict__ dstf, int R, int C, int writeF) {
    __shared__ float tile[32][33];
    const int c0 = blockIdx.x * 32, r0 = blockIdx.y * 32;
    const int tx = threadIdx.x % 32, ty = threadIdx.x / 32;
#pragma unroll
    for (int i = ty; i < 32; i += 8)
        tile[i][tx] = src[(size_t)(r0 + i) * C + c0 + tx];
    __syncthreads();
#pragma unroll
    for (int i = ty; i < 32; i += 8) {
        float v = tile[tx][i];
        size_t o = (size_t)(c0 + i) * R + r0 + tx;
        dstb[o] = f32_to_bf16_rne(v);
        if (writeF) dstf[o] = v;
    }
}

// -------- bf16 MFMA GEMM, 3-buffer pipeline w/ counted vmcnt ---------------
// 128x128 tile, BK=32, 4 waves (2x2). Depth-2 prefetch stays in flight
// across raw s_barrier; per-iter waits: vmcnt(8)/(4)/(0) by distance to end.
// L2-aware XCD mapping (xcd owns gridDim.y/8 contiguous by-rows).
template<bool RELU, bool WF32, bool WBF16>
__global__ __launch_bounds__(256)
void gemm_mfma(const unsigned short* __restrict__ A,
               const unsigned short* __restrict__ Bt,
               const float* __restrict__ bias,
               float* __restrict__ C, unsigned short* __restrict__ Cb,
               int M, int N, int K) {
    constexpr int BM = 128, BN = 128, BK = 32;
    constexpr int TSZ = BM * BK;
    __shared__ unsigned short As[3 * TSZ];
    __shared__ unsigned short Bs[3 * TSZ];

    const int lid = blockIdx.y * gridDim.x + blockIdx.x;
    const int xcd = lid & 7;
    const int kk2 = lid >> 3;
    const int rpx = gridDim.y >> 3;
    const int by = xcd * rpx + (kk2 % rpx);
    const int bx = kk2 / rpx;

    const int tid = threadIdx.x;
    const int wid = tid >> 6;
    const int lane = tid & 63;
    const int wr = wid >> 1, wc = wid & 1;
    const int l15 = lane & 15, lq = lane >> 4;
    const int brow = by * BM;
    const int bcol = bx * BN;

    const int g1 = tid;
    const int g2 = tid + 256;
    const size_t a1 = (size_t)(brow + (g1 >> 2)) * K + (g1 & 3) * 8;
    const size_t a2 = (size_t)(brow + (g2 >> 2)) * K + (g2 & 3) * 8;
    const size_t b1 = (size_t)(bcol + (g1 >> 2)) * K + (g1 & 3) * 8;
    const size_t b2 = (size_t)(bcol + (g2 >> 2)) * K + (g2 & 3) * 8;
    const int off1 = wid * 64 * 8;
    const int off2 = (256 + wid * 64) * 8;

    f32x4 acc[4][4];
#pragma unroll
    for (int m = 0; m < 4; ++m)
#pragma unroll
        for (int n = 0; n < 4; ++n) acc[m][n] = (f32x4){0.f, 0.f, 0.f, 0.f};

    const int NK = K / BK;

#define STAGE(kt, bufi) { \
    const int k0_ = (kt) * BK; \
    const int o_ = (bufi) * TSZ; \
    gload16(A + a1 + k0_, As + o_ + off1); \
    gload16(A + a2 + k0_, As + o_ + off2); \
    gload16(Bt + b1 + k0_, Bs + o_ + off1); \
    gload16(Bt + b2 + k0_, Bs + o_ + off2); }

    STAGE(0, 0)
    if (NK > 1) STAGE(1, 1)

    int buf = 0;
    for (int kt = 0; kt < NK; ++kt) {
        if (kt + 2 < NK) {
            int nb = buf + 2; if (nb >= 3) nb -= 3;
            STAGE(kt + 2, nb)
        }
        if (kt + 2 < NK)      asm volatile("s_waitcnt vmcnt(8)" ::: "memory");
        else if (kt + 1 < NK) asm volatile("s_waitcnt vmcnt(4)" ::: "memory");
        else                  asm volatile("s_waitcnt vmcnt(0)" ::: "memory");
        __builtin_amdgcn_s_barrier();
        __builtin_amdgcn_sched_barrier(0);

        const int cb = buf * TSZ;
        short8v af[4], bf[4];
#pragma unroll
        for (int m = 0; m < 4; ++m)
            af[m] = *(const short8v*)&As[cb + (wr * 64 + m * 16 + l15) * BK + lq * 8];
#pragma unroll
        for (int n = 0; n < 4; ++n)
            bf[n] = *(const short8v*)&Bs[cb + (wc * 64 + n * 16 + l15) * BK + lq * 8];
#pragma unroll
        for (int m = 0; m < 4; ++m)
#pragma unroll
            for (int n = 0; n < 4; ++n)
                acc[m][n] = __builtin_amdgcn_mfma_f32_16x16x32_bf16(
                    af[m], bf[n], acc[m][n], 0, 0, 0);
        __builtin_amdgcn_s_barrier();
        ++buf; if (buf == 3) buf = 0;
    }
#undef STAGE

#pragma unroll
    for (int m = 0; m < 4; ++m) {
#pragma unroll
        for (int n = 0; n < 4; ++n) {
            int col = bcol + wc * 64 + n * 16 + l15;
            float bv = bias[col];
#pragma unroll
            for (int r = 0; r < 4; ++r) {
                int row = brow + wr * 64 + m * 16 + lq * 4 + r;
                float v = acc[m][n][r] + bv;
                if (RELU) v = fmaxf(v, 0.0f);
                if (WF32) C[(size_t)row * N + col] = v;
                if (WBF16) Cb[(size_t)row * N + col] = f32_to_bf16_rne(v);
            }
        }
    }
}

// -------- sampler v5: max-only + ballot recovery (1 wave / token) ----------
// Ties are flagged ambiguous (count>=2) and resolved exactly by refine, so
// no tie-break or top-2 bookkeeping is needed here.
__global__ __launch_bounds__(256)
void sample_tokens_max(const float* __restrict__ z, int* __restrict__ tokens,
                       float* __restrict__ s1v, int* __restrict__ amb,
                       int* __restrict__ ambCount) {
    const int wave = threadIdx.x >> 6;
    const int lane = threadIdx.x & 63;
    const uint32_t t = blockIdx.x * 4 + wave;
    const float* zr = z + (size_t)t * VOCAB;

    float sc[8];
    float m = -INFINITY;
#pragma unroll
    for (int half = 0; half < 2; ++half) {
        const int e0 = half * 256 + lane * 4;
        const float4 zv = *(const float4*)&zr[e0];
        uint32_t b0, b1, b2, b3;
        threefry4x(t * (uint32_t)VOCAB + (uint32_t)e0, b0, b1, b2, b3);
        sc[half * 4 + 0] = zv.x + gumbel_from_bits(b0);
        sc[half * 4 + 1] = zv.y + gumbel_from_bits(b1);
        sc[half * 4 + 2] = zv.z + gumbel_from_bits(b2);
        sc[half * 4 + 3] = zv.w + gumbel_from_bits(b3);
        m = fmaxf(m, fmaxf(fmaxf(sc[half * 4 + 0], sc[half * 4 + 1]),
                           fmaxf(sc[half * 4 + 2], sc[half * 4 + 3])));
    }
#pragma unroll
    for (int off = 32; off > 0; off >>= 1)
        m = fmaxf(m, __shfl_xor(m, off));

    const float thr = m - MARGIN;
    int nge = 0;
    int vsel = VOCAB;
#pragma unroll
    for (int idx = 0; idx < 8; ++idx) {
        unsigned long long mge = __ballot(sc[idx] >= thr);
        nge += __popcll(mge);
        unsigned long long meq = __ballot(sc[idx] == m);
        if (vsel == VOCAB && meq) {
            int ln = __builtin_ctzll(meq);
            vsel = (idx >> 2) * 256 + ln * 4 + (idx & 3);
        }
    }
    if (lane == 0) {
        tokens[t] = vsel;
        s1v[t] = m;
        if (nge >= 2) {
            int idx = atomicAdd(ambCount, 1);
            amb[idx] = (int)t;
        }
    }
}

// ------ refine: w2t f32 rows, ballot-compacted candidates ------------------
__global__ __launch_bounds__(64)
void refine_tokens2(const float* __restrict__ z, const float* __restrict__ h,
                    const float* __restrict__ w2t, const float* __restrict__ eb2,
                    const int* __restrict__ amb, const int* __restrict__ ambCount,
                    const float* __restrict__ s1v, int* __restrict__ tok) {
    __shared__ float hrow[DMODEL];
    __shared__ int candv[64];
    const int cnt = *ambCount;
    const int lane = threadIdx.x;

    for (int i = blockIdx.x; i < cnt; i += gridDim.x) {
        const int t = amb[i];
        const int b = t >> 5;
        const int kb = t & 31;
        const float* zr = z + (size_t)t * VOCAB;
        const float s1 = s1v[t];

        {
            float4 hv0 = *(const float4*)&h[(size_t)b * DMODEL + lane * 8];
            float4 hv1 = *(const float4*)&h[(size_t)b * DMODEL + lane * 8 + 4];
            *(float4*)&hrow[lane * 8] = hv0;
            *(float4*)&hrow[lane * 8 + 4] = hv1;
        }

        int base = 0;
#pragma unroll
        for (int half = 0; half < 2; ++half) {
            int e0 = half * 256 + lane * 4;
            float4 zv = *(const float4*)&zr[e0];
            float zs[4] = {zv.x, zv.y, zv.z, zv.w};
#pragma unroll
            for (int j = 0; j < 4; ++j) {
                int v = e0 + j;
                float s = zs[j] + fast_gumbel((uint32_t)t * VOCAB + v);
                bool pred = (s >= s1 - MARGIN);
                unsigned long long mask = __ballot(pred);
                if (pred) {
                    int slot = base + __popcll(mask & ((1ull << lane) - 1ull));
                    if (slot < 64) candv[slot] = v;
                }
                base += __popcll(mask);
            }
        }
        __syncthreads();
        const int ncand = base < 64 ? base : 64;

        float bestE = -INFINITY;
        int bestV = VOCAB;
        if (lane < ncand) {
            const int v = candv[lane];
            const int n = kb * VOCAB + v;
            const float* wr_ = w2t + (size_t)n * DMODEL;
            float acc = 0.f;
#pragma unroll 8
            for (int k = 0; k < DMODEL; ++k)
                acc = fmaf(hrow[k], wr_[k], acc);
            bestE = acc + eb2[n] + jax_gumbel((uint64_t)t * VOCAB + v);
            bestV = v;
        }
#pragma unroll
        for (int off = 32; off > 0; off >>= 1) {
            float oe = __shfl_down(bestE, off);
            int ov = __shfl_down(bestV, off);
            if (oe > bestE || (oe == bestE && ov < bestV)) { bestE = oe; bestV = ov; }
        }
        if (lane == 0) tok[t] = bestV;
        __syncthreads();
    }
}

// ----------------- simple sampler (ws-too-small fallback) ------------------
__global__ __launch_bounds__(256)
void sample_tokens_simple(const float* __restrict__ z, int* __restrict__ tokens) {
    const int wave = threadIdx.x >> 6;
    const int lane = threadIdx.x & 63;
    const size_t t = (size_t)blockIdx.x * 4 + wave;
    const float* zr = z + t * VOCAB;
    float zv[8];
    *(float4*)&zv[0] = *(const float4*)&zr[lane * 8];
    *(float4*)&zv[4] = *(const float4*)&zr[lane * 8 + 4];
    const uint64_t ebase = t * (uint64_t)VOCAB + (uint64_t)lane * 8;
    float best = -INFINITY;
    int bestv = 0;
#pragma unroll
    for (int j = 0; j < 8; ++j) {
        float g = jax_gumbel(ebase + j);
        float s = zv[j] + g;
        int v = lane * 8 + j;
        if (s > best || (s == best && v < bestv)) { best = s; bestv = v; }
    }
#pragma unroll
    for (int off = 32; off > 0; off >>= 1) {
        float ob = __shfl_down(best, off);
        int ov = __shfl_down(bestv, off);
        if (ob > best || (ob == best && ov < bestv)) { best = ob; bestv = ov; }
    }
    if (lane == 0) tokens[t] = bestv;
}

__global__ __launch_bounds__(64)
void zero_count(int* p) { if (threadIdx.x == 0) *p = 0; }

// ---------------- z_q gather (exact f32 + optional bf16 copy) --------------
__global__ __launch_bounds__(256)
void gather_zq(const int* __restrict__ tokens, const float* __restrict__ codebook,
               float* __restrict__ zq, unsigned short* __restrict__ zqb) {
    const int b = blockIdx.x;
    const int d = threadIdx.x;
    float s = 0.0f;
#pragma unroll
    for (int k = 0; k < KTOK; ++k) {
        int tok = tokens[b * KTOK + k];
        s += codebook[(size_t)(k * VOCAB + tok) * EDIM + d];
    }
    zq[(size_t)b * EDIM + d] = s;
    if (zqb) zqb[(size_t)b * EDIM + d] = f32_to_bf16_rne(s);
}

// ------------------------------- launcher ----------------------------------
extern "C" void kernel_launch(void* const* d_in, const int* in_sizes, int n_in,
                              void* d_out, int out_size, void* d_ws, size_t ws_size,
                              hipStream_t stream) {
    const float* x   = (const float*)d_in[0];
    const float* ew1 = (const float*)d_in[1];
    const float* eb1 = (const float*)d_in[2];
    const float* ew2 = (const float*)d_in[3];
    const float* eb2 = (const float*)d_in[4];
    const float* cb  = (const float*)d_in[5];
    const float* dw1 = (const float*)d_in[6];
    const float* db1 = (const float*)d_in[7];
    const float* dw2 = (const float*)d_in[8];
    const float* db2 = (const float*)d_in[9];

    float* out = (float*)d_out;
    float* z   = out;
    float* zq  = out + (size_t)BATCH * ZDIM;
    float* rec = zq + (size_t)BATCH * EDIM;

    char* ws = (char*)d_ws;
    float* h    = (float*)(ws);                               // 8 MB
    unsigned short* zqb   = (unsigned short*)(ws + 8388608);  // 2 MB
    unsigned short* h2b   = (unsigned short*)(ws + 10485760); // 4 MB
    unsigned short* dw1tb = (unsigned short*)(ws + 14680064); // 256 KB
    unsigned short* dw2tb = (unsigned short*)(ws + 14942208); // 512 KB
    float* h2f  = (float*)(ws + 8388608);                     // fallback f32 h2
    unsigned short* hb   = (unsigned short*)(ws + 16777216);  // 4 MB
    unsigned short* w2bt = (unsigned short*)(ws + 20971520);  // 16 MB
    float* w2t  = (float*)(ws + 37748736);                    // 32 MB
    char* tail = ws + 71303168;
    const size_t WS_NEED2 = 71303168 + 1572864 + 256;         // ~72.9 MB
    const bool fast2 = ws_size >= WS_NEED2;
    if (!fast2) tail = ws + 16777216;
    int*   tok  = (int*)(tail);
    float* s1v  = (float*)(tail + 524288);
    int*   amb  = (int*)(tail + 1048576);
    int*   cnt  = (int*)(tail + 1572864);

    dim3 blk(256);

    // encoder layer 1 (f32 exact; bf16 copy fused when fast2)
    gemm_f32_64<true ><<<dim3(DMODEL / 64, BATCH / 64), blk, 0, stream>>>(
        x, ew1, eb1, h, fast2 ? hb : (unsigned short*)nullptr,
        BATCH, DMODEL, DMODEL);

    if (fast2) {
        transpose_w2<<<dim3(ZDIM / 32, DMODEL / 32), blk, 0, stream>>>(
            ew2, w2bt, w2t, DMODEL, ZDIM, 1);
        transpose_w2<<<dim3(DMODEL / 32, EDIM / 32), blk, 0, stream>>>(
            dw1, dw1tb, nullptr, EDIM, DMODEL, 0);
        transpose_w2<<<dim3(DMODEL / 32, DMODEL / 32), blk, 0, stream>>>(
            dw2, dw2tb, nullptr, DMODEL, DMODEL, 0);
        zero_count<<<dim3(1), dim3(64), 0, stream>>>(cnt);
        // big GEMM -> z
        gemm_mfma<false, true, false><<<dim3(ZDIM / 128, BATCH / 128), blk, 0, stream>>>(
            hb, w2bt, eb2, z, nullptr, BATCH, ZDIM, DMODEL);
        sample_tokens_max<<<dim3(BATCH * KTOK / 4), blk, 0, stream>>>(
            z, tok, s1v, amb, cnt);
        refine_tokens2<<<dim3(4096), dim3(64), 0, stream>>>(
            z, h, w2t, eb2, amb, cnt, s1v, tok);
        gather_zq<<<dim3(BATCH), blk, 0, stream>>>(tok, cb, zq, zqb);
        // decoder via bf16 MFMA
        gemm_mfma<true, false, true><<<dim3(DMODEL / 128, BATCH / 128), blk, 0, stream>>>(
            zqb, dw1tb, db1, nullptr, h2b, BATCH, DMODEL, EDIM);
        gemm_mfma<false, true, false><<<dim3(DMODEL / 128, BATCH / 128), blk, 0, stream>>>(
            h2b, dw2tb, db2, rec, nullptr, BATCH, DMODEL, DMODEL);
    } else {
        gemm_f32<false><<<dim3(ZDIM / 128, BATCH / 128), blk, 0, stream>>>(
            h, ew2, eb2, z, BATCH, ZDIM, DMODEL);
        sample_tokens_simple<<<dim3(BATCH * KTOK / 4), blk, 0, stream>>>(z, tok);
        gather_zq<<<dim3(BATCH), blk, 0, stream>>>(tok, cb, zq, nullptr);
        gemm_f32_64<true ><<<dim3(DMODEL / 64, BATCH / 64), blk, 0, stream>>>(
            zq, dw1, db1, h2f, nullptr, BATCH, DMODEL, EDIM);
        gemm_f32_64<false><<<dim3(DMODEL / 64, BATCH / 64), blk, 0, stream>>>(
            h2f, dw2, db2, rec, nullptr, BATCH, DMODEL, DMODEL);
    }
}